// Round 7
// baseline (349.396 us; speedup 1.0000x reference)
//
#include <hip/hip_runtime.h>

// ---------------------------------------------------------------------------
// RingDilatedAttentionSDPA: B=1, S=8192, E=1024, H=16, D=64
// segments: (len=2048,dil=1), (4096,2), (8192->2048,4); mean of scattered outs
// Pipeline: cvt f32->bf16 ; QKV GEMM -> Q(pre-scaled log2e/8),K,V [h][s][d] ;
// transpose_v -> 3 key-permuted V^T dilation copies ; single flash launch,
// 768 equal-length blocks (seg2 split into additive K-halves: no-max softmax
// makes (o,l) partials additive) computing S^T=K.Q^T and O^T=V^T.P^T ;
// combine (merges seg2 halves via stored l) ; out GEMM.
// ---------------------------------------------------------------------------

typedef __attribute__((ext_vector_type(8))) short bf16x8;   // 8 bf16 in 4 VGPRs
typedef __attribute__((ext_vector_type(4))) float f32x4;

#define MFMA(a, b, c) __builtin_amdgcn_mfma_f32_16x16x32_bf16((a), (b), (c), 0, 0, 0)

#if __has_builtin(__builtin_amdgcn_exp2f)
#define EXP2(x) __builtin_amdgcn_exp2f(x)
#else
#define EXP2(x) exp2f(x)
#endif

static __device__ __forceinline__ unsigned short f2bf(float f) {
  unsigned int u = __float_as_uint(f);
  unsigned int r = (u + 0x7FFFu + ((u >> 16) & 1u)) >> 16;  // RNE
  return (unsigned short)r;
}

// ---------------------------- f32 -> bf16 convert --------------------------
__global__ void cvt_f32_bf16(const float* __restrict__ in,
                             unsigned short* __restrict__ out, int n8) {
  int i = blockIdx.x * blockDim.x + threadIdx.x;
  if (i >= n8) return;
  const float4* p = (const float4*)in + (size_t)i * 2;
  float4 a = p[0];
  float4 b = p[1];
  union { bf16x8 v; unsigned short u[8]; } o;
  o.u[0] = f2bf(a.x); o.u[1] = f2bf(a.y); o.u[2] = f2bf(a.z); o.u[3] = f2bf(a.w);
  o.u[4] = f2bf(b.x); o.u[5] = f2bf(b.y); o.u[6] = f2bf(b.z); o.u[7] = f2bf(b.w);
  *((bf16x8*)out + i) = o.v;
}

// ------------------------------- GEMM (C = A.B^T + bias) -------------------
// EPILOGUE 0: qkv [3][16][8192][64] bf16, Q scaled by log2e/8; 1: f32 rowmaj.
template <int EPILOGUE>
__global__ __launch_bounds__(256, 2) void gemm_bt(
    const unsigned short* __restrict__ A, const unsigned short* __restrict__ B,
    const float* __restrict__ bias, void* __restrict__ Cout, int N, int K) {
  __shared__ unsigned short At[128 * 32];
  __shared__ unsigned short Bt[128 * 32];
  const int tid = threadIdx.x;
  const int wave = tid >> 6, lane = tid & 63;
  const int quad = lane >> 4, lc = lane & 15;
  const int wm = (wave >> 1) * 64, wn = (wave & 1) * 64;
  const int m0 = blockIdx.x * 128, n0 = blockIdx.y * 128;

  f32x4 acc[4][4] = {};

  for (int k0 = 0; k0 < K; k0 += 32) {
    __syncthreads();
#pragma unroll
    for (int issue = 0; issue < 2; ++issue) {
      const int cbase = issue * 256 + wave * 64;
      const int c = cbase + lane;
      const int row = c >> 2, col8 = (c & 3) * 8;   // 128 rows x 32 cols
      __builtin_amdgcn_global_load_lds(
          (const __attribute__((address_space(1))) void*)&A[(size_t)(m0 + row) * K + k0 + col8],
          (__attribute__((address_space(3))) void*)&At[cbase * 8], 16, 0, 0);
      __builtin_amdgcn_global_load_lds(
          (const __attribute__((address_space(1))) void*)&B[(size_t)(n0 + row) * K + k0 + col8],
          (__attribute__((address_space(3))) void*)&Bt[cbase * 8], 16, 0, 0);
    }
    __syncthreads();
    bf16x8 af[4], bfr[4];
#pragma unroll
    for (int t = 0; t < 4; ++t)
      af[t] = *(const bf16x8*)&At[(wm + t * 16 + lc) * 32 + quad * 8];
#pragma unroll
    for (int t = 0; t < 4; ++t)
      bfr[t] = *(const bf16x8*)&Bt[(wn + t * 16 + lc) * 32 + quad * 8];
#pragma unroll
    for (int i = 0; i < 4; ++i)
#pragma unroll
      for (int j = 0; j < 4; ++j)
        acc[i][j] = MFMA(af[i], bfr[j], acc[i][j]);
  }

#pragma unroll
  for (int i = 0; i < 4; ++i) {
#pragma unroll
    for (int j = 0; j < 4; ++j) {
      const int gcol = n0 + wn + j * 16 + lc;
      const float bs = bias[gcol];
#pragma unroll
      for (int r = 0; r < 4; ++r) {
        const int grow = m0 + wm + i * 16 + quad * 4 + r;
        const float v = acc[i][j][r] + bs;
        if (EPILOGUE == 0) {
          const int which = gcol >> 10, rem = gcol & 1023;
          const int hh = rem >> 6, d = rem & 63;
          // Q gets 1/sqrt(D) * log2(e) folded in (exp2 softmax downstream)
          const float vs = (which == 0) ? v * 0.18033688f : v;
          ((unsigned short*)Cout)[(((size_t)(which * 16 + hh)) * 8192 + grow) * 64 + d] = f2bf(vs);
        } else {
          ((float*)Cout)[(size_t)grow * N + gcol] = v;
        }
      }
    }
  }
}

// ---------------- V transpose: [h][s][d] -> key-permuted [h][d][n] ---------
// perm within each 32-block: position p holds key 16*((p>>2)&1)+4*(p>>3)+(p&3)
// (matches the P^T B-fragment register order of the flash kernel).
__global__ void transpose_v(const unsigned short* __restrict__ v,
                            unsigned short* __restrict__ vt1,
                            unsigned short* __restrict__ vt2,
                            unsigned short* __restrict__ vt3) {
  __shared__ unsigned short Tt[64 * 72];
  const int tid = threadIdx.x;
  const int h = blockIdx.y;
  const int bx = blockIdx.x;
  const unsigned short* src = v + (size_t)h * 8192 * 64;
  unsigned short* dst;
  int dil, Nk, t0;
  if (bx < 32)      { dst = vt1; dil = 1; Nk = 2048; t0 = bx; }
  else if (bx < 96) { dst = vt2; dil = 2; Nk = 4096; t0 = bx - 32; }
  else              { dst = vt3; dil = 4; Nk = 2048; t0 = bx - 96; }
  dst += (size_t)h * 64 * Nk;
  const int j0 = t0 * 64;
#pragma unroll
  for (int it = 0; it < 2; ++it) {
    const int slot = tid + it * 256;
    const int jj = slot >> 3, c8 = (slot & 7) * 8;
    *(bf16x8*)&Tt[jj * 72 + c8] =
        *(const bf16x8*)&src[(size_t)(j0 + jj) * dil * 64 + c8];
  }
  __syncthreads();
  const int d = tid >> 2, pg = (tid & 3) * 16;
  union { bf16x8 v2[2]; unsigned short u[16]; } ob;
#pragma unroll
  for (int t = 0; t < 16; ++t) {
    const int pos = pg + t;
    const int w = pos & 31;
    const int jj = (pos & 32) | (((w >> 2) & 1) * 16 + (w >> 3) * 4 + (w & 3));
    ob.u[t] = Tt[jj * 72 + d];
  }
  *(bf16x8*)&dst[(size_t)d * Nk + j0 + pg] = ob.v2[0];
  *(bf16x8*)&dst[(size_t)d * Nk + j0 + pg + 8] = ob.v2[1];
}

// --------------------------- flash attention, all segments -----------------
// 768 equal blocks of 2048 keys: bx = 3*i + r. r<2: seg2 (h=i>>4, qt=i&15),
// K-half r (additive partials -> o2a/o2b raw + l2a/l2b). r==2: i<128 seg1,
// else seg3 (self-normalized, /3l folded). S^T = K.Q^T (A=K from LDS, B=Q
// registers); O^T = V^T.P^T (P^T built in-register from packed exp2 C-regs,
// key-perm in vt makes layouts coincide). XOR-swizzled conflict-free LDS.
__global__ __launch_bounds__(256, 3) void flash_all(
    const unsigned short* __restrict__ qkvb,
    const unsigned short* __restrict__ vt1, float* __restrict__ o1,
    const unsigned short* __restrict__ vt2, float* __restrict__ o2a,
    float* __restrict__ o2b, float* __restrict__ l2a, float* __restrict__ l2b,
    const unsigned short* __restrict__ vt3, float* __restrict__ o3) {
  __shared__ unsigned short Smem[2 * 64 * 64];  // Kt | Vt ; epilogue: f32 O^T
  unsigned short* Kt = Smem;
  unsigned short* Vt = Smem + 64 * 64;

  const int bx = blockIdx.x;
  const int i = bx / 3;
  const int r = bx - 3 * i;
  int z, h, qt, kb0;
  const unsigned short* vt;
  float* o;
  float* lout = nullptr;
  if (r < 2) {
    z = 1; h = i >> 4; qt = i & 15; kb0 = r * 2048;
    vt = vt2; o = (r == 0) ? o2a : o2b; lout = (r == 0) ? l2a : l2b;
  } else if (i < 128) {
    z = 0; h = i >> 3; qt = i & 7; kb0 = 0; vt = vt1; o = o1;
  } else {
    const int j = i - 128;
    z = 2; h = j >> 3; qt = j & 7; kb0 = 0; vt = vt3; o = o3;
  }
  const int Nk = (z == 1) ? 4096 : 2048;        // vt row stride
  const int kbEnd = kb0 + 2048;
  const int dil = 1 << z;
  const bool split = (r < 2);

  const int tid = threadIdx.x;
  const int wave = tid >> 6, lane = tid & 63;
  const int quad = lane >> 4, lc = lane & 15;

  const unsigned short* qh = qkvb + (size_t)h * 8192 * 64;
  const unsigned short* kh = qkvb + (size_t)(16 + h) * 8192 * 64;
  const unsigned short* vh = vt + (size_t)h * 64 * Nk;

  // Q B-fragments: 4 m-blocks of 16 q (B[n=lc][k=quad*8+j], halves d<32,>=32)
  bf16x8 qf[4][2];
#pragma unroll
  for (int mb = 0; mb < 4; ++mb) {
    const size_t qrow = (size_t)(qt * 256 + wave * 64 + mb * 16 + lc) * dil;
    qf[mb][0] = *(const bf16x8*)&qh[qrow * 64 + quad * 8];
    qf[mb][1] = *(const bf16x8*)&qh[qrow * 64 + quad * 8 + 32];
  }

  // constant all-ones A fragment (bf16 1.0) for the row-sum (l) MFMA
  union { bf16x8 v; unsigned short u[8]; } one_u;
#pragma unroll
  for (int t = 0; t < 8; ++t) one_u.u[t] = 0x3F80;
  const bf16x8 vone = one_u.v;

  f32x4 oacc[4][4] = {};   // [mb][nb]  O^T C-tiles: row=d, col=q
  f32x4 lacc[4] = {};      // [mb]      l per q (all rows identical)

  // staging: 512 slots of 16B per tile-pair; swizzled chunk = scol ^ (row&7)
  const int srow = tid >> 3, scol = tid & 7;
  const int swz = (scol ^ (srow & 7)) * 8;

  bf16x8 kg0 = *(const bf16x8*)&kh[(size_t)((kb0 + srow) * dil) * 64 + scol * 8];
  bf16x8 kg1 = *(const bf16x8*)&kh[(size_t)((kb0 + srow + 32) * dil) * 64 + scol * 8];
  bf16x8 vg0 = *(const bf16x8*)&vh[(size_t)srow * Nk + kb0 + scol * 8];
  bf16x8 vg1 = *(const bf16x8*)&vh[(size_t)(srow + 32) * Nk + kb0 + scol * 8];

  for (int kb = kb0; kb < kbEnd; kb += 64) {
    __syncthreads();
    *(bf16x8*)&Kt[srow * 64 + swz] = kg0;
    *(bf16x8*)&Kt[(srow + 32) * 64 + swz] = kg1;
    *(bf16x8*)&Vt[srow * 64 + swz] = vg0;
    *(bf16x8*)&Vt[(srow + 32) * 64 + swz] = vg1;
    __syncthreads();

    if (kb + 64 < kbEnd) {   // prefetch next tile into registers
      const int nk = kb + 64;
      kg0 = *(const bf16x8*)&kh[(size_t)((nk + srow) * dil) * 64 + scol * 8];
      kg1 = *(const bf16x8*)&kh[(size_t)((nk + srow + 32) * dil) * 64 + scol * 8];
      vg0 = *(const bf16x8*)&vh[(size_t)srow * Nk + nk + scol * 8];
      vg1 = *(const bf16x8*)&vh[(size_t)(srow + 32) * Nk + nk + scol * 8];
    }

#pragma unroll
    for (int ks = 0; ks < 2; ++ks) {         // two 32-key subsets
      // ---- S^T tiles: D[m=key][n=q] = K.Q^T ----
      f32x4 st[2][4];
#pragma unroll
      for (int t = 0; t < 2; ++t) {
        const int row = (ks * 2 + t) * 16 + lc;
        const bf16x8 ka0 = *(const bf16x8*)&Kt[row * 64 + ((quad ^ (lc & 7)) * 8)];
        const bf16x8 ka1 = *(const bf16x8*)&Kt[row * 64 + (((4 + quad) ^ (lc & 7)) * 8)];
#pragma unroll
        for (int mb = 0; mb < 4; ++mb) {
          f32x4 zz = {};
          zz = MFMA(ka0, qf[mb][0], zz);
          st[t][mb] = MFMA(ka1, qf[mb][1], zz);
        }
      }

      // ---- p = exp2(s); pack -> P^T B-frags (register order == vt key perm)
      bf16x8 pb[4];
#pragma unroll
      for (int mb = 0; mb < 4; ++mb) {
        union { bf16x8 v; unsigned int u[4]; } pu;
#pragma unroll
        for (int t = 0; t < 2; ++t) {
          const unsigned int a0 = __float_as_uint(EXP2(st[t][mb][0])) + 0x8000u;
          const unsigned int a1 = __float_as_uint(EXP2(st[t][mb][1])) + 0x8000u;
          const unsigned int a2 = __float_as_uint(EXP2(st[t][mb][2])) + 0x8000u;
          const unsigned int a3 = __float_as_uint(EXP2(st[t][mb][3])) + 0x8000u;
          pu.u[t * 2 + 0] = __builtin_amdgcn_perm(a1, a0, 0x07060302u);
          pu.u[t * 2 + 1] = __builtin_amdgcn_perm(a3, a2, 0x07060302u);
        }
        pb[mb] = pu.v;
      }

      // ---- O^T += V^T.P^T ; l += 1.P^T ----
#pragma unroll
      for (int nb = 0; nb < 4; ++nb) {
        const int vrow = nb * 16 + lc;
        const bf16x8 va = *(const bf16x8*)&Vt[vrow * 64 + (((ks * 4 + quad) ^ (lc & 7)) * 8)];
#pragma unroll
        for (int mb = 0; mb < 4; ++mb)
          oacc[mb][nb] = MFMA(va, pb[mb], oacc[mb][nb]);
      }
#pragma unroll
      for (int mb = 0; mb < 4; ++mb) lacc[mb] = MFMA(vone, pb[mb], lacc[mb]);
    }
  }

  // ---- epilogue: O^T -> O via swizzled LDS transpose, coalesced stores ----
  __syncthreads();                       // all waves done reading Kt/Vt
  float* W = (float*)Smem + wave * 16 * 64;   // per-wave 16q x 64d region
  const int g = lane >> 2, s4 = lane & 3;
#pragma unroll
  for (int mb = 0; mb < 4; ++mb) {
    // split halves store RAW o and l (additive); others fold 1/(3l)
    const float inv = split ? 1.0f : 1.0f / (3.0f * lacc[mb][0]);
    if (split && quad == 0)
      lout[(size_t)h * 4096 + qt * 256 + wave * 64 + mb * 16 + lc] = lacc[mb][0];
#pragma unroll
    for (int nb = 0; nb < 4; ++nb) {
      const int c = nb * 4 + quad;
      const int cs = (c & 8) | ((c & 7) ^ (lc & 7));
      f32x4 val = oacc[mb][nb];
      val *= inv;
      *(f32x4*)&W[lc * 64 + cs * 4] = val;
    }
    // read back transposed (same-wave ds ordering via lgkmcnt)
    const size_t base = (size_t)(qt * 256 + wave * 64 + mb * 16 + g) * 1024 +
                        (size_t)h * 64 + s4 * 16;
#pragma unroll
    for (int c2 = 0; c2 < 4; ++c2) {
      const int c = s4 * 4 + c2;
      const int cs = (c & 8) | ((c & 7) ^ (g & 7));
      *(float4*)&o[base + c2 * 4] = *(const float4*)&W[g * 64 + cs * 4];
    }
  }
}

// ------------------- combine per-seg outputs -> bf16 a3 --------------------
__global__ void combine(const float* __restrict__ o1,
                        const float* __restrict__ o2a, const float* __restrict__ o2b,
                        const float* __restrict__ l2a, const float* __restrict__ l2b,
                        const float* __restrict__ o3,
                        unsigned short* __restrict__ a3b) {
  const int idx = blockIdx.x * 256 + threadIdx.x;   // 8192*128
  const int s = idx >> 7, e = (idx & 127) * 8;
  float acc[8] = {};
  if (s < 2048) {
    const float* p = &o1[(size_t)s * 1024 + e];
#pragma unroll
    for (int t = 0; t < 8; ++t) acc[t] += p[t];
  }
  if (!(s & 1)) {
    const int j = s >> 1, hh = e >> 6;
    const float la = l2a[(size_t)hh * 4096 + j];
    const float lb = l2b[(size_t)hh * 4096 + j];
    const float w = 1.0f / (3.0f * (la + lb));
    const float* pa = &o2a[(size_t)j * 1024 + e];
    const float* pb = &o2b[(size_t)j * 1024 + e];
#pragma unroll
    for (int t = 0; t < 8; ++t) acc[t] += (pa[t] + pb[t]) * w;
  }
  if (!(s & 3)) {
    const float* p = &o3[(size_t)(s >> 2) * 1024 + e];
#pragma unroll
    for (int t = 0; t < 8; ++t) acc[t] += p[t];
  }
  union { bf16x8 v; unsigned short u[8]; } ob;
#pragma unroll
  for (int t = 0; t < 8; ++t) ob.u[t] = f2bf(acc[t]);
  *(bf16x8*)&a3b[(size_t)s * 1024 + e] = ob.v;
}

// ---------------------------------------------------------------------------
extern "C" void kernel_launch(void* const* d_in, const int* in_sizes, int n_in,
                              void* d_out, int out_size, void* d_ws, size_t ws_size,
                              hipStream_t stream) {
  const float* x     = (const float*)d_in[0];  // [8192][1024]
  const float* w_qkv = (const float*)d_in[1];  // [3072][1024]
  const float* b_qkv = (const float*)d_in[2];  // [3072]
  const float* w_out = (const float*)d_in[3];  // [1024][1024]
  const float* b_out = (const float*)d_in[4];  // [1024]
  float* out = (float*)d_out;                  // [8192][1024] f32

  char* ws = (char*)d_ws;
  unsigned short* qkvb  = (unsigned short*)(ws);             // Q,K,V: 50,331,648 B
  // V third (33,554,432..50,331,648) dead after transpose_v -> o1/o3:
  float*          o1    = (float*)(ws + 33554432);           //  8,388,608 B
  float*          o3    = (float*)(ws + 41943040);           //  8,388,608 B
  unsigned short* vt1   = (unsigned short*)(ws + 50331648);  //  4,194,304 B
  unsigned short* vt2   = (unsigned short*)(ws + 54525952);  //  8,388,608 B
  unsigned short* vt3   = (unsigned short*)(ws + 62914560);  //  4,194,304 B
  float*          o2a   = (float*)(ws + 67108864);           // 16,777,216 B
  unsigned short* wqkvb = (unsigned short*)(ws + 83886080);  //  6,291,456 B; dead after gemm<0>:
  float*          l2a   = (float*)(ws + 83886080);           //    262,144 B (over wqkvb)
  float*          l2b   = (float*)(ws + 84148224);           //    262,144 B (over wqkvb)
  unsigned short* woutb = (unsigned short*)(ws + 90177536);  //  2,097,152 B
  unsigned short* xb    = (unsigned short*)(ws + 92274688);  // 16,777,216 B; dead after gemm<0>:
  float*          o2b   = (float*)(ws + 92274688);           // 16,777,216 B (over xb)
  unsigned short* a3b   = (unsigned short*)(ws + 50331648);  // 16,777,216 B (over vt*, dead after flash)

  cvt_f32_bf16<<<dim3(8388608 / 8 / 256), dim3(256), 0, stream>>>(x, xb, 8388608 / 8);
  cvt_f32_bf16<<<dim3(3145728 / 8 / 256), dim3(256), 0, stream>>>(w_qkv, wqkvb, 3145728 / 8);
  cvt_f32_bf16<<<dim3(1048576 / 8 / 256), dim3(256), 0, stream>>>(w_out, woutb, 1048576 / 8);

  // QKV projection -> [3][16][8192][64] (Q pre-scaled by log2e/8)
  gemm_bt<0><<<dim3(64, 24), dim3(256), 0, stream>>>(xb, wqkvb, b_qkv, qkvb, 3072, 1024);

  // V -> key-permuted transposed dilation copies
  transpose_v<<<dim3(128, 16), dim3(256), 0, stream>>>(qkvb + (size_t)32 * 8192 * 64,
                                                       vt1, vt2, vt3);

  // all 3 attention segments, 768 equal-length blocks (3 blocks/CU)
  flash_all<<<dim3(768), dim3(256), 0, stream>>>(qkvb, vt1, o1, vt2, o2a, o2b,
                                                 l2a, l2b, vt3, o3);

  // merge segment outputs (seg2 halves via l2a/l2b) -> bf16
  combine<<<dim3(4096), dim3(256), 0, stream>>>(o1, o2a, o2b, l2a, l2b, o3, a3b);

  // output projection: out = a3 . woutb^T + b_out   (f32 out)
  gemm_bt<1><<<dim3(64, 8), dim3(256), 0, stream>>>(a3b, woutb, b_out, out, 1024, 1024);
}

// Round 8
// 341.053 us; speedup vs baseline: 1.0245x; 1.0245x over previous
//
#include <hip/hip_runtime.h>

// ---------------------------------------------------------------------------
// RingDilatedAttentionSDPA: B=1, S=8192, E=1024, H=16, D=64
// segments: (len=2048,dil=1), (4096,2), (8192->2048,4); mean of scattered outs
// Pipeline: cvt_all f32->bf16 ; QKV GEMM (C^T epilogue, vectorized stores) ->
// Q(pre-scaled log2e/8),K,V [h][s][d] ; transpose_v -> 3 key-permuted V^T
// copies ; flash (768 equal blocks, XCD-aware h mapping, double-buffered LDS,
// S^T=K.Q^T / O^T=V^T.P^T, in-register P^T) ; combine ; out GEMM (C^T).
// ---------------------------------------------------------------------------

typedef __attribute__((ext_vector_type(8))) short bf16x8;   // 8 bf16 in 4 VGPRs
typedef __attribute__((ext_vector_type(4))) float f32x4;

#define MFMA(a, b, c) __builtin_amdgcn_mfma_f32_16x16x32_bf16((a), (b), (c), 0, 0, 0)

#if __has_builtin(__builtin_amdgcn_exp2f)
#define EXP2(x) __builtin_amdgcn_exp2f(x)
#else
#define EXP2(x) exp2f(x)
#endif

static __device__ __forceinline__ unsigned short f2bf(float f) {
  unsigned int u = __float_as_uint(f);
  unsigned int r = (u + 0x7FFFu + ((u >> 16) & 1u)) >> 16;  // RNE
  return (unsigned short)r;
}

// ---------------------------- f32 -> bf16 convert (fused 3 tensors) --------
__global__ void cvt_all(const float* __restrict__ x, const float* __restrict__ wq,
                        const float* __restrict__ wo,
                        unsigned short* __restrict__ xb,
                        unsigned short* __restrict__ wqb,
                        unsigned short* __restrict__ wob) {
  int i = blockIdx.x * 256 + threadIdx.x;     // 1572864 slots of 8 elems
  const float* src;
  unsigned short* dst;
  if (i < 1048576) { src = x; dst = xb; }
  else if (i < 1441792) { src = wq + (size_t)(i - 1048576) * 8 - 0; dst = wqb; i -= 1048576; src = wq; }
  else { i -= 1441792; src = wo; dst = wob; }
  const float4* p = (const float4*)src + (size_t)i * 2;
  float4 a = p[0];
  float4 b = p[1];
  union { bf16x8 v; unsigned short u[8]; } o;
  o.u[0] = f2bf(a.x); o.u[1] = f2bf(a.y); o.u[2] = f2bf(a.z); o.u[3] = f2bf(a.w);
  o.u[4] = f2bf(b.x); o.u[5] = f2bf(b.y); o.u[6] = f2bf(b.z); o.u[7] = f2bf(b.w);
  *((bf16x8*)dst + i) = o.v;
}

// ------------------------------- GEMM (C = A.B^T + bias) -------------------
// Computes C^T tiles: D=MFMA(B-frag, A-frag) -> rows=features, cols=s.
// Lane's 4 C-regs are 4 CONSECUTIVE features -> vectorized epilogue stores.
// EPILOGUE 0: qkv [3][16][8192][64] bf16 (Q scaled log2e/8), 8B stores;
// EPILOGUE 1: f32 row-major, 16B stores.
template <int EPILOGUE>
__global__ __launch_bounds__(256, 2) void gemm_bt(
    const unsigned short* __restrict__ A, const unsigned short* __restrict__ B,
    const float* __restrict__ bias, void* __restrict__ Cout, int N, int K) {
  __shared__ unsigned short At[128 * 32];
  __shared__ unsigned short Bt[128 * 32];
  const int tid = threadIdx.x;
  const int wave = tid >> 6, lane = tid & 63;
  const int quad = lane >> 4, lc = lane & 15;
  const int wm = (wave >> 1) * 64, wn = (wave & 1) * 64;
  const int m0 = blockIdx.x * 128, n0 = blockIdx.y * 128;

  f32x4 acc[4][4] = {};

  for (int k0 = 0; k0 < K; k0 += 32) {
    __syncthreads();
#pragma unroll
    for (int issue = 0; issue < 2; ++issue) {
      const int cbase = issue * 256 + wave * 64;
      const int c = cbase + lane;
      const int row = c >> 2, col8 = (c & 3) * 8;   // 128 rows x 32 cols
      __builtin_amdgcn_global_load_lds(
          (const __attribute__((address_space(1))) void*)&A[(size_t)(m0 + row) * K + k0 + col8],
          (__attribute__((address_space(3))) void*)&At[cbase * 8], 16, 0, 0);
      __builtin_amdgcn_global_load_lds(
          (const __attribute__((address_space(1))) void*)&B[(size_t)(n0 + row) * K + k0 + col8],
          (__attribute__((address_space(3))) void*)&Bt[cbase * 8], 16, 0, 0);
    }
    __syncthreads();
    bf16x8 af[4], bfr[4];
#pragma unroll
    for (int t = 0; t < 4; ++t)
      af[t] = *(const bf16x8*)&At[(wm + t * 16 + lc) * 32 + quad * 8];
#pragma unroll
    for (int t = 0; t < 4; ++t)
      bfr[t] = *(const bf16x8*)&Bt[(wn + t * 16 + lc) * 32 + quad * 8];
#pragma unroll
    for (int i = 0; i < 4; ++i)
#pragma unroll
      for (int j = 0; j < 4; ++j)
        acc[i][j] = MFMA(bfr[j], af[i], acc[i][j]);   // C^T: rows=feat, cols=s
  }

#pragma unroll
  for (int j = 0; j < 4; ++j) {
    const int nc0 = n0 + wn + j * 16 + quad * 4;      // 4 consecutive features
    const float4 bs4 = *(const float4*)&bias[nc0];
    if (EPILOGUE == 0) {
      // which/hh wave-uniform per j (64-aligned wave col-block)
      const int which = nc0 >> 10, rem = nc0 & 1023;
      const int hh = rem >> 6, d0 = rem & 63;
      const float sc = (which == 0) ? 0.18033688f : 1.0f;  // log2e/8 for Q
      unsigned short* base =
          (unsigned short*)Cout + ((size_t)(which * 16 + hh)) * 8192 * 64 + d0;
#pragma unroll
      for (int i = 0; i < 4; ++i) {
        const int grow = m0 + wm + i * 16 + lc;
        const unsigned int p0 = __float_as_uint((acc[i][j][0] + bs4.x) * sc) + 0x8000u;
        const unsigned int p1 = __float_as_uint((acc[i][j][1] + bs4.y) * sc) + 0x8000u;
        const unsigned int p2 = __float_as_uint((acc[i][j][2] + bs4.z) * sc) + 0x8000u;
        const unsigned int p3 = __float_as_uint((acc[i][j][3] + bs4.w) * sc) + 0x8000u;
        uint2 w;
        w.x = __builtin_amdgcn_perm(p1, p0, 0x07060302u);
        w.y = __builtin_amdgcn_perm(p3, p2, 0x07060302u);
        *(uint2*)(base + (size_t)grow * 64) = w;
      }
    } else {
      float* op = (float*)Cout;
#pragma unroll
      for (int i = 0; i < 4; ++i) {
        const int grow = m0 + wm + i * 16 + lc;
        float4 v;
        v.x = acc[i][j][0] + bs4.x;
        v.y = acc[i][j][1] + bs4.y;
        v.z = acc[i][j][2] + bs4.z;
        v.w = acc[i][j][3] + bs4.w;
        *(float4*)&op[(size_t)grow * N + nc0] = v;
      }
    }
  }
}

// ---------------- V transpose: [h][s][d] -> key-permuted [h][d][n] ---------
// perm within each 32-block: position p holds key 16*((p>>2)&1)+4*(p>>3)+(p&3)
// (matches the P^T B-fragment register order of the flash kernel).
__global__ void transpose_v(const unsigned short* __restrict__ v,
                            unsigned short* __restrict__ vt1,
                            unsigned short* __restrict__ vt2,
                            unsigned short* __restrict__ vt3) {
  __shared__ unsigned short Tt[64 * 72];
  const int tid = threadIdx.x;
  const int h = blockIdx.y;
  const int bx = blockIdx.x;
  const unsigned short* src = v + (size_t)h * 8192 * 64;
  unsigned short* dst;
  int dil, Nk, t0;
  if (bx < 32)      { dst = vt1; dil = 1; Nk = 2048; t0 = bx; }
  else if (bx < 96) { dst = vt2; dil = 2; Nk = 4096; t0 = bx - 32; }
  else              { dst = vt3; dil = 4; Nk = 2048; t0 = bx - 96; }
  dst += (size_t)h * 64 * Nk;
  const int j0 = t0 * 64;
#pragma unroll
  for (int it = 0; it < 2; ++it) {
    const int slot = tid + it * 256;
    const int jj = slot >> 3, c8 = (slot & 7) * 8;
    *(bf16x8*)&Tt[jj * 72 + c8] =
        *(const bf16x8*)&src[(size_t)(j0 + jj) * dil * 64 + c8];
  }
  __syncthreads();
  const int d = tid >> 2, pg = (tid & 3) * 16;
  union { bf16x8 v2[2]; unsigned short u[16]; } ob;
#pragma unroll
  for (int t = 0; t < 16; ++t) {
    const int pos = pg + t;
    const int w = pos & 31;
    const int jj = (pos & 32) | (((w >> 2) & 1) * 16 + (w >> 3) * 4 + (w & 3));
    ob.u[t] = Tt[jj * 72 + d];
  }
  *(bf16x8*)&dst[(size_t)d * Nk + j0 + pg] = ob.v2[0];
  *(bf16x8*)&dst[(size_t)d * Nk + j0 + pg + 8] = ob.v2[1];
}

// --------------------------- flash attention, all segments -----------------
// 768 equal blocks of 2048 keys, XCD-aware: x=bx&7 selects head pair {x,x+8}
// so same-head blocks share an XCD L2 slice. Per head-slot g: g<32 seg2-half,
// 32..39 seg1, 40..47 seg3. S^T=K.Q^T ; O^T=V^T.P^T (P^T in-register from
// truncation-packed exp2 C-regs; key perm in vt matches). Double-buffered
// XOR-swizzled LDS (one barrier per tile). l via ones-A-frag MFMA.
__global__ __launch_bounds__(256, 3) void flash_all(
    const unsigned short* __restrict__ qkvb,
    const unsigned short* __restrict__ vt1, float* __restrict__ o1,
    const unsigned short* __restrict__ vt2, float* __restrict__ o2a,
    float* __restrict__ o2b, float* __restrict__ l2a, float* __restrict__ l2b,
    const unsigned short* __restrict__ vt3, float* __restrict__ o3) {
  __shared__ unsigned short Smem[2][2 * 64 * 64];  // dbuf: Kt|Vt ; epi: f32 O^T

  const int bx = blockIdx.x;
  const int x = bx & 7, g = bx >> 3;
  const int h = x + ((g >= 48) ? 8 : 0);
  const int gg = (g >= 48) ? g - 48 : g;
  int z, qt, kb0;
  const unsigned short* vt;
  float* o;
  float* lout = nullptr;
  bool split = false;
  if (gg < 32) {
    z = 1; qt = gg >> 1; kb0 = (gg & 1) * 2048; split = true;
    vt = vt2; o = (gg & 1) ? o2b : o2a; lout = (gg & 1) ? l2b : l2a;
  } else if (gg < 40) {
    z = 0; qt = gg - 32; kb0 = 0; vt = vt1; o = o1;
  } else {
    z = 2; qt = gg - 40; kb0 = 0; vt = vt3; o = o3;
  }
  const int Nk = (z == 1) ? 4096 : 2048;        // vt row stride
  const int kbEnd = kb0 + 2048;
  const int dil = 1 << z;

  const int tid = threadIdx.x;
  const int wave = tid >> 6, lane = tid & 63;
  const int quad = lane >> 4, lc = lane & 15;

  const unsigned short* qh = qkvb + (size_t)h * 8192 * 64;
  const unsigned short* kh = qkvb + (size_t)(16 + h) * 8192 * 64;
  const unsigned short* vh = vt + (size_t)h * 64 * Nk;

  // Q B-fragments: 4 m-blocks of 16 q (B[n=lc][k=quad*8+j], halves d<32,>=32)
  bf16x8 qf[4][2];
#pragma unroll
  for (int mb = 0; mb < 4; ++mb) {
    const size_t qrow = (size_t)(qt * 256 + wave * 64 + mb * 16 + lc) * dil;
    qf[mb][0] = *(const bf16x8*)&qh[qrow * 64 + quad * 8];
    qf[mb][1] = *(const bf16x8*)&qh[qrow * 64 + quad * 8 + 32];
  }

  // constant all-ones A fragment (bf16 1.0) for the row-sum (l) MFMA
  union { bf16x8 v; unsigned short u[8]; } one_u;
#pragma unroll
  for (int t = 0; t < 8; ++t) one_u.u[t] = 0x3F80;
  const bf16x8 vone = one_u.v;

  f32x4 oacc[4][4] = {};   // [mb][nb]  O^T C-tiles: row=d, col=q
  f32x4 lacc[4] = {};      // [mb]      l per q (all rows identical)

  // staging: 512 slots of 16B per tile-pair; swizzled chunk = scol ^ (row&7)
  const int srow = tid >> 3, scol = tid & 7;
  const int swz = (scol ^ (srow & 7)) * 8;

  // initial tile -> regs -> buf0
  bf16x8 kg0 = *(const bf16x8*)&kh[(size_t)((kb0 + srow) * dil) * 64 + scol * 8];
  bf16x8 kg1 = *(const bf16x8*)&kh[(size_t)((kb0 + srow + 32) * dil) * 64 + scol * 8];
  bf16x8 vg0 = *(const bf16x8*)&vh[(size_t)srow * Nk + kb0 + scol * 8];
  bf16x8 vg1 = *(const bf16x8*)&vh[(size_t)(srow + 32) * Nk + kb0 + scol * 8];
  *(bf16x8*)&Smem[0][srow * 64 + swz] = kg0;
  *(bf16x8*)&Smem[0][(srow + 32) * 64 + swz] = kg1;
  *(bf16x8*)&Smem[0][4096 + srow * 64 + swz] = vg0;
  *(bf16x8*)&Smem[0][4096 + (srow + 32) * 64 + swz] = vg1;
  __syncthreads();

  int p = 0;
  for (int kb = kb0; kb < kbEnd; kb += 64) {
    const bool more = (kb + 64 < kbEnd);
    if (more) {   // prefetch next tile into registers (latency hidden by compute)
      const int nk = kb + 64;
      kg0 = *(const bf16x8*)&kh[(size_t)((nk + srow) * dil) * 64 + scol * 8];
      kg1 = *(const bf16x8*)&kh[(size_t)((nk + srow + 32) * dil) * 64 + scol * 8];
      vg0 = *(const bf16x8*)&vh[(size_t)srow * Nk + nk + scol * 8];
      vg1 = *(const bf16x8*)&vh[(size_t)(srow + 32) * Nk + nk + scol * 8];
    }
    const unsigned short* Kt = Smem[p];
    const unsigned short* Vt = Smem[p] + 4096;

#pragma unroll
    for (int ks = 0; ks < 2; ++ks) {         // two 32-key subsets
      // ---- S^T tiles: D[m=key][n=q] = K.Q^T ----
      f32x4 st[2][4];
#pragma unroll
      for (int t = 0; t < 2; ++t) {
        const int row = (ks * 2 + t) * 16 + lc;
        const bf16x8 ka0 = *(const bf16x8*)&Kt[row * 64 + ((quad ^ (lc & 7)) * 8)];
        const bf16x8 ka1 = *(const bf16x8*)&Kt[row * 64 + (((4 + quad) ^ (lc & 7)) * 8)];
#pragma unroll
        for (int mb = 0; mb < 4; ++mb) {
          f32x4 zz = {};
          zz = MFMA(ka0, qf[mb][0], zz);
          st[t][mb] = MFMA(ka1, qf[mb][1], zz);
        }
      }

      // ---- p = exp2(s); truncation-pack -> P^T B-frags (order == vt perm)
      // (truncation bias cancels in o = sum(p v)/sum(p))
      bf16x8 pb[4];
#pragma unroll
      for (int mb = 0; mb < 4; ++mb) {
        union { bf16x8 v; unsigned int u[4]; } pu;
#pragma unroll
        for (int t = 0; t < 2; ++t) {
          const unsigned int a0 = __float_as_uint(EXP2(st[t][mb][0]));
          const unsigned int a1 = __float_as_uint(EXP2(st[t][mb][1]));
          const unsigned int a2 = __float_as_uint(EXP2(st[t][mb][2]));
          const unsigned int a3 = __float_as_uint(EXP2(st[t][mb][3]));
          pu.u[t * 2 + 0] = __builtin_amdgcn_perm(a1, a0, 0x07060302u);
          pu.u[t * 2 + 1] = __builtin_amdgcn_perm(a3, a2, 0x07060302u);
        }
        pb[mb] = pu.v;
      }

      // ---- O^T += V^T.P^T ; l += 1.P^T ----
#pragma unroll
      for (int nb = 0; nb < 4; ++nb) {
        const int vrow = nb * 16 + lc;
        const bf16x8 va = *(const bf16x8*)&Vt[vrow * 64 + (((ks * 4 + quad) ^ (lc & 7)) * 8)];
#pragma unroll
        for (int mb = 0; mb < 4; ++mb)
          oacc[mb][nb] = MFMA(va, pb[mb], oacc[mb][nb]);
      }
#pragma unroll
      for (int mb = 0; mb < 4; ++mb) lacc[mb] = MFMA(vone, pb[mb], lacc[mb]);
    }

    if (more) {   // store next tile into the other buffer
      *(bf16x8*)&Smem[p ^ 1][srow * 64 + swz] = kg0;
      *(bf16x8*)&Smem[p ^ 1][(srow + 32) * 64 + swz] = kg1;
      *(bf16x8*)&Smem[p ^ 1][4096 + srow * 64 + swz] = vg0;
      *(bf16x8*)&Smem[p ^ 1][4096 + (srow + 32) * 64 + swz] = vg1;
    }
    __syncthreads();
    p ^= 1;
  }

  // ---- epilogue: O^T -> O via swizzled LDS transpose, coalesced stores ----
  float* W = (float*)Smem + wave * 16 * 64;   // per-wave 16q x 64d region
  const int g2 = lane >> 2, s4 = lane & 3;
#pragma unroll
  for (int mb = 0; mb < 4; ++mb) {
    // split halves store RAW o and l (additive); others fold 1/(3l)
    const float inv = split ? 1.0f : 1.0f / (3.0f * lacc[mb][0]);
    if (split && quad == 0)
      lout[(size_t)h * 4096 + qt * 256 + wave * 64 + mb * 16 + lc] = lacc[mb][0];
#pragma unroll
    for (int nb = 0; nb < 4; ++nb) {
      const int c = nb * 4 + quad;
      const int cs = (c & 8) | ((c & 7) ^ (lc & 7));
      f32x4 val = oacc[mb][nb];
      val *= inv;
      *(f32x4*)&W[lc * 64 + cs * 4] = val;
    }
    // read back transposed (same-wave ds ordering via lgkmcnt)
    const size_t base = (size_t)(qt * 256 + wave * 64 + mb * 16 + g2) * 1024 +
                        (size_t)h * 64 + s4 * 16;
#pragma unroll
    for (int c2 = 0; c2 < 4; ++c2) {
      const int c = s4 * 4 + c2;
      const int cs = (c & 8) | ((c & 7) ^ (g2 & 7));
      *(float4*)&o[base + c2 * 4] = *(const float4*)&W[g2 * 64 + cs * 4];
    }
  }
}

// ------------------- combine per-seg outputs -> bf16 a3 --------------------
__global__ void combine(const float* __restrict__ o1,
                        const float* __restrict__ o2a, const float* __restrict__ o2b,
                        const float* __restrict__ l2a, const float* __restrict__ l2b,
                        const float* __restrict__ o3,
                        unsigned short* __restrict__ a3b) {
  const int idx = blockIdx.x * 256 + threadIdx.x;   // 8192*128
  const int s = idx >> 7, e = (idx & 127) * 8;
  float acc[8] = {};
  if (s < 2048) {
    const float* p = &o1[(size_t)s * 1024 + e];
#pragma unroll
    for (int t = 0; t < 8; ++t) acc[t] += p[t];
  }
  if (!(s & 1)) {
    const int j = s >> 1, hh = e >> 6;
    const float la = l2a[(size_t)hh * 4096 + j];
    const float lb = l2b[(size_t)hh * 4096 + j];
    const float w = 1.0f / (3.0f * (la + lb));
    const float* pa = &o2a[(size_t)j * 1024 + e];
    const float* pb = &o2b[(size_t)j * 1024 + e];
#pragma unroll
    for (int t = 0; t < 8; ++t) acc[t] += (pa[t] + pb[t]) * w;
  }
  if (!(s & 3)) {
    const float* p = &o3[(size_t)(s >> 2) * 1024 + e];
#pragma unroll
    for (int t = 0; t < 8; ++t) acc[t] += p[t];
  }
  union { bf16x8 v; unsigned short u[8]; } ob;
#pragma unroll
  for (int t = 0; t < 8; ++t) ob.u[t] = f2bf(acc[t]);
  *(bf16x8*)&a3b[(size_t)s * 1024 + e] = ob.v;
}

// ---------------------------------------------------------------------------
extern "C" void kernel_launch(void* const* d_in, const int* in_sizes, int n_in,
                              void* d_out, int out_size, void* d_ws, size_t ws_size,
                              hipStream_t stream) {
  const float* x     = (const float*)d_in[0];  // [8192][1024]
  const float* w_qkv = (const float*)d_in[1];  // [3072][1024]
  const float* b_qkv = (const float*)d_in[2];  // [3072]
  const float* w_out = (const float*)d_in[3];  // [1024][1024]
  const float* b_out = (const float*)d_in[4];  // [1024]
  float* out = (float*)d_out;                  // [8192][1024] f32

  char* ws = (char*)d_ws;
  unsigned short* qkvb  = (unsigned short*)(ws);             // Q,K,V: 50,331,648 B
  // V third (33,554,432..50,331,648) dead after transpose_v -> o1/o3:
  float*          o1    = (float*)(ws + 33554432);           //  8,388,608 B
  float*          o3    = (float*)(ws + 41943040);           //  8,388,608 B
  unsigned short* vt1   = (unsigned short*)(ws + 50331648);  //  4,194,304 B
  unsigned short* vt2   = (unsigned short*)(ws + 54525952);  //  8,388,608 B
  unsigned short* vt3   = (unsigned short*)(ws + 62914560);  //  4,194,304 B
  float*          o2a   = (float*)(ws + 67108864);           // 16,777,216 B
  unsigned short* wqkvb = (unsigned short*)(ws + 83886080);  //  6,291,456 B; dead after gemm<0>:
  float*          l2a   = (float*)(ws + 83886080);           //    262,144 B (over wqkvb)
  float*          l2b   = (float*)(ws + 84148224);           //    262,144 B (over wqkvb)
  unsigned short* woutb = (unsigned short*)(ws + 90177536);  //  2,097,152 B
  unsigned short* xb    = (unsigned short*)(ws + 92274688);  // 16,777,216 B; dead after gemm<0>:
  float*          o2b   = (float*)(ws + 92274688);           // 16,777,216 B (over xb)
  unsigned short* a3b   = (unsigned short*)(ws + 50331648);  // 16,777,216 B (over vt*, dead after flash)

  // fused f32->bf16 conversions (x, w_qkv, w_out)
  cvt_all<<<dim3(6144), dim3(256), 0, stream>>>(x, w_qkv, w_out, xb, wqkvb, woutb);

  // QKV projection -> [3][16][8192][64] (Q pre-scaled by log2e/8)
  gemm_bt<0><<<dim3(64, 24), dim3(256), 0, stream>>>(xb, wqkvb, b_qkv, qkvb, 3072, 1024);

  // V -> key-permuted transposed dilation copies
  transpose_v<<<dim3(128, 16), dim3(256), 0, stream>>>(qkvb + (size_t)32 * 8192 * 64,
                                                       vt1, vt2, vt3);

  // all 3 attention segments, 768 equal-length blocks (3 blocks/CU, XCD-aware)
  flash_all<<<dim3(768), dim3(256), 0, stream>>>(qkvb, vt1, o1, vt2, o2a, o2b,
                                                 l2a, l2b, vt3, o3);

  // merge segment outputs (seg2 halves via l2a/l2b) -> bf16
  combine<<<dim3(4096), dim3(256), 0, stream>>>(o1, o2a, o2b, l2a, l2b, o3, a3b);

  // output projection: out = a3 . woutb^T + b_out   (f32 out)
  gemm_bt<1><<<dim3(64, 8), dim3(256), 0, stream>>>(a3b, woutb, b_out, out, 1024, 1024);
}